// Round 5
// baseline (1323.942 us; speedup 1.0000x reference)
//
#include <hip/hip_runtime.h>

#define N_NODES 100000
#define N_EDGES 1600000
#define D 128
#define NBUCKET 8
#define BUCKET_W 12500          // N_NODES / NBUCKET
#define CAP 216000              // per-bucket record capacity (E/8 = 200k, sigma~420)
#define CHUNK 2048              // edges per binA block
#define PB_BLOCKS_PER 192       // passB blocks per bucket

typedef __attribute__((ext_vector_type(8))) short short8;
typedef __attribute__((ext_vector_type(4))) float float4v;

__device__ inline unsigned short f2bf(float f) {
    unsigned u = __float_as_uint(f);
    unsigned r = (u + 0x7fffu + ((u >> 16) & 1u)) >> 16;   // RNE
    return (unsigned short)r;
}
__device__ inline float bflo(unsigned int p) { return __uint_as_float(p << 16); }
__device__ inline float bfhi(unsigned int p) { return __uint_as_float(p & 0xffff0000u); }

// dtype probe: bf16 (flag=1) vs fp32 (flag=0)
__global__ void probe_kernel(const unsigned int* __restrict__ xw, int* __restrict__ flag) {
    __shared__ int cnt;
    if (threadIdx.x == 0) cnt = 0;
    __syncthreads();
    unsigned int low = xw[threadIdx.x] & 0xFFFFu;
    unsigned int e = (low >> 7) & 0xFFu;
    atomicAdd(&cnt, (e == 0u) || (e >= 107u && e <= 147u));
    __syncthreads();
    if (threadIdx.x == 0) *flag = (cnt >= 192) ? 1 : 0;
}

__global__ void convert_b_kernel(const void* __restrict__ b, const int* __restrict__ flag,
                                 float* __restrict__ bfv) {
    int i = threadIdx.x;
    if (i < D)
        bfv[i] = *flag ? bflo(((const unsigned short*)b)[i]) : ((const float*)b)[i];
}

// Pass A: coarse-bin edges into 8 buckets (block-private contiguous appends -> full-line
// writebacks); also counts deg. Two LDS-staged sweeps per 2048-edge chunk.
__global__ void binA_kernel(const int* __restrict__ src, const int* __restrict__ dst,
                            int* __restrict__ bcnt, int* __restrict__ deg,
                            int2* __restrict__ rec) {
    __shared__ int lcnt[NBUCKET], lbase[NBUCKET];
    int tid = threadIdx.x;
    int e0 = blockIdx.x * CHUNK;
    int eend = e0 + CHUNK < N_EDGES ? e0 + CHUNK : N_EDGES;
    if (tid < NBUCKET) lcnt[tid] = 0;
    __syncthreads();
    for (int i = e0 + tid; i < eend; i += 256)
        atomicAdd(&lcnt[dst[i] / BUCKET_W], 1);
    __syncthreads();
    if (tid < NBUCKET) { lbase[tid] = atomicAdd(&bcnt[tid], lcnt[tid]); lcnt[tid] = 0; }
    __syncthreads();
    for (int i = e0 + tid; i < eend; i += 256) {
        int d = dst[i], s = src[i];
        int g = d / BUCKET_W;
        int pos = lbase[g] + atomicAdd(&lcnt[g], 1);
        if (pos < CAP) rec[(size_t)g * CAP + pos] = make_int2(s, d);
        atomicAdd(&deg[d], 1);
    }
}

__global__ void prefix_kernel(const int* __restrict__ bcnt, int* __restrict__ bucket_base) {
    if (threadIdx.x == 0) {
        int s = 0;
        for (int g = 0; g < NBUCKET; ++g) { bucket_base[g] = s; s += bcnt[g]; }
    }
}

// row_start within the node's bucket region (bucket-contiguous lists); dis fused in.
__global__ void rowstart_kernel(const int* __restrict__ deg, const int* __restrict__ bucket_base,
                                int* __restrict__ bcur, int* __restrict__ row_start,
                                int* __restrict__ cur, float* __restrict__ dis) {
    int i = blockIdx.x * 256 + threadIdx.x;
    if (i < N_NODES) {
        int dgi = deg[i];
        int g = i / BUCKET_W;
        int rs = bucket_base[g] + atomicAdd(&bcur[g], dgi);
        row_start[i] = rs;
        cur[i] = rs;
        dis[i] = rsqrtf((float)(dgi + 1));   // +1 self-loop
    }
}

// Pass B: fine scatter, XCD-pinned (bucket = blockIdx%8) so each bucket's ~800KB fine
// region stays in ONE XCD L2 and partial-line writes merge.
__global__ void passB_kernel(const int2* __restrict__ rec, const int* __restrict__ bcnt,
                             int* __restrict__ cur, int* __restrict__ esrc) {
    int g = blockIdx.x & 7;
    int slice = blockIdx.x >> 3;
    int total = bcnt[g];
    const int2* r = rec + (size_t)g * CAP;
    for (int i = slice * 256 + threadIdx.x; i < total; i += PB_BLOCKS_PER * 256) {
        int2 e = r[i];
        int pos = atomicAdd(&cur[e.y], 1);
        esrc[pos] = e.x;
    }
}

// h' = (x @ W) * dis[row] -> bf16 bits. MFMA 16x16x32 bf16, one wave per 16-row strip.
__global__ void gemm_kernel(const void* __restrict__ xv, const void* __restrict__ Wv,
                            const int* __restrict__ flag, const float* __restrict__ dis,
                            unsigned short* __restrict__ h) {
    __shared__ unsigned short Wt[D * 136];  // W transposed [col][k], stride 136
    int tid = threadIdx.x;
    int m = *flag;
    for (int idx = tid; idx < D * D; idx += 256) {
        int k = idx >> 7, c = idx & 127;
        Wt[c * 136 + k] = m ? ((const unsigned short*)Wv)[idx]
                            : f2bf(((const float*)Wv)[idx]);
    }
    __syncthreads();

    int wave = tid >> 6, lane = tid & 63;
    int row0 = (blockIdx.x * 4 + wave) * 16;
    if (row0 >= N_NODES) return;
    int r = lane & 15, quad = lane >> 4;

    short8 a[4];  // a[t][j] = x[row0+r][t*32 + quad*8 + j]
    if (m) {
        const unsigned short* xr = (const unsigned short*)xv + (size_t)(row0 + r) * D + quad * 8;
        #pragma unroll
        for (int t = 0; t < 4; ++t) a[t] = *(const short8*)(xr + t * 32);
    } else {
        const float* xr = (const float*)xv + (size_t)(row0 + r) * D + quad * 8;
        #pragma unroll
        for (int t = 0; t < 4; ++t)
            for (int j = 0; j < 8; ++j) a[t][j] = (short)f2bf(xr[t * 32 + j]);
    }

    float sc[4];
    #pragma unroll
    for (int reg = 0; reg < 4; ++reg) sc[reg] = dis[row0 + quad * 4 + reg];

    #pragma unroll
    for (int ct = 0; ct < 8; ++ct) {
        int col0 = ct * 16;
        float4v c = {0.f, 0.f, 0.f, 0.f};
        #pragma unroll
        for (int t = 0; t < 4; ++t) {
            short8 bfr = *(const short8*)&Wt[(col0 + r) * 136 + t * 32 + quad * 8];
            c = __builtin_amdgcn_mfma_f32_16x16x32_bf16(a[t], bfr, c, 0, 0, 0);
        }
        #pragma unroll
        for (int reg = 0; reg < 4; ++reg) {
            int orow = row0 + quad * 4 + reg;  // C/D: col=lane&15, row=quad*4+reg
            h[(size_t)orow * D + col0 + r] = f2bf(c[reg] * sc[reg]);
        }
    }
}

// Quarter-wave aggregate: 16 lanes x dwordx4 per h row, 4 edges in flight per iteration;
// butterfly (xor 16,32) combine; out = relu(dis[n]*acc + b).
__global__ void aggregate_kernel(const int* __restrict__ esrc, const int* __restrict__ row_start,
                                 const int* __restrict__ deg, const float* __restrict__ dis,
                                 const float* __restrict__ bfv, const int* __restrict__ flag,
                                 const unsigned short* __restrict__ h, void* __restrict__ out) {
    int n = blockIdx.x * 4 + (threadIdx.x >> 6);
    if (n >= N_NODES) return;
    int lane = threadIdx.x & 63;
    int q = lane >> 4, c16 = lane & 15;
    int colbase = c16 * 8;           // 8 bf16 columns per lane

    float acc[8];
    if (q == 0) {                    // self term (dis[src] folded into h')
        uint4 p = *(const uint4*)(h + (size_t)n * D + colbase);
        acc[0] = bflo(p.x); acc[1] = bfhi(p.x);
        acc[2] = bflo(p.y); acc[3] = bfhi(p.y);
        acc[4] = bflo(p.z); acc[5] = bfhi(p.z);
        acc[6] = bflo(p.w); acc[7] = bfhi(p.w);
    } else {
        #pragma unroll
        for (int i = 0; i < 8; ++i) acc[i] = 0.f;
    }

    int rs = row_start[n], dg = deg[n];
    for (int base = 0; base < dg; base += 64) {
        int rem = dg - base;
        int cnt = rem < 64 ? rem : 64;
        int e_my = (lane < cnt) ? esrc[rs + base + lane] : 0;
        for (int j = 0; j < cnt; j += 4) {
            int sl = j + q;                  // which edge this quarter handles
            int s = __shfl(e_my, sl & 63);
            if (sl < cnt) {
                uint4 p = *(const uint4*)(h + (size_t)s * D + colbase);
                acc[0] += bflo(p.x); acc[1] += bfhi(p.x);
                acc[2] += bflo(p.y); acc[3] += bfhi(p.y);
                acc[4] += bflo(p.z); acc[5] += bfhi(p.z);
                acc[6] += bflo(p.w); acc[7] += bfhi(p.w);
            }
        }
    }

    #pragma unroll
    for (int i = 0; i < 8; ++i) {
        acc[i] += __shfl_xor(acc[i], 16);
        acc[i] += __shfl_xor(acc[i], 32);
    }

    float dn = dis[n];
    float v[8];
    #pragma unroll
    for (int i = 0; i < 8; ++i) v[i] = fmaxf(dn * acc[i] + bfv[colbase + i], 0.f);

    if (*flag) {
        if (q == 0) {
            uint4 pk;
            pk.x = ((unsigned)f2bf(v[1]) << 16) | f2bf(v[0]);
            pk.y = ((unsigned)f2bf(v[3]) << 16) | f2bf(v[2]);
            pk.z = ((unsigned)f2bf(v[5]) << 16) | f2bf(v[4]);
            pk.w = ((unsigned)f2bf(v[7]) << 16) | f2bf(v[6]);
            *(uint4*)((unsigned short*)out + (size_t)n * D + colbase) = pk;
        }
    } else {
        if (q < 2) {                 // fp32 row = 512B: q0 writes first 16B, q1 last 16B
            float4 f;
            int off = q * 4;
            f.x = v[off]; f.y = v[off + 1]; f.z = v[off + 2]; f.w = v[off + 3];
            *(float4*)((float*)out + (size_t)n * D + colbase + off) = f;
        }
    }
}

extern "C" void kernel_launch(void* const* d_in, const int* in_sizes, int n_in,
                              void* d_out, int out_size, void* d_ws, size_t ws_size,
                              hipStream_t stream) {
    const void* x = nullptr; const int* ei = nullptr;
    const void* W = nullptr; const void* b = nullptr;
    for (int i = 0; i < n_in; ++i) {
        if      (in_sizes[i] == N_NODES * D) x  = d_in[i];
        else if (in_sizes[i] == 2 * N_EDGES) ei = (const int*)d_in[i];
        else if (in_sizes[i] == D * D)       W  = d_in[i];
        else if (in_sizes[i] == D)           b  = d_in[i];
    }
    if (!x || !ei || !W || !b) {
        x = d_in[0]; ei = (const int*)d_in[1]; W = d_in[2]; b = d_in[3];
    }
    const int* src = ei;            // edge_index[0]
    const int* dst = ei + N_EDGES;  // edge_index[1]

    // ws: flag(16) | bcnt 8 | bcur 8 | bucket_base 8 | deg N | cur N | row_start N |
    //     dis N f32 | bfv 128 f32 | esrc E | rec 8*CAP int2 | h N*D bf16   (~47 MB)
    char* ws = (char*)d_ws;
    int*   flag        = (int*)ws;                       // 16 B
    int*   bcnt        = (int*)(ws + 16);                // 8
    int*   bcur        = bcnt + NBUCKET;                 // 8  (memset with bcnt: 64B)
    int*   bucket_base = bcur + NBUCKET;                 // 8  (written by prefix)
    int*   deg         = bucket_base + NBUCKET + 8;      // N  (align)
    int*   cur         = deg + N_NODES;
    int*   row_start   = cur + N_NODES;
    float* dis         = (float*)(row_start + N_NODES);
    float* bfv         = dis + N_NODES;
    int*   esrc        = (int*)(bfv + D);
    int2*  rec         = (int2*)(esrc + N_EDGES);
    unsigned short* h  = (unsigned short*)(rec + (size_t)NBUCKET * CAP);

    hipMemsetAsync(deg, 0, sizeof(int) * N_NODES, stream);
    hipMemsetAsync(bcnt, 0, sizeof(int) * 2 * NBUCKET, stream);   // bcnt + bcur

    probe_kernel<<<1, 256, 0, stream>>>((const unsigned int*)x, flag);
    convert_b_kernel<<<1, 256, 0, stream>>>(b, flag, bfv);

    binA_kernel<<<(N_EDGES + CHUNK - 1) / CHUNK, 256, 0, stream>>>(src, dst, bcnt, deg, rec);
    prefix_kernel<<<1, 64, 0, stream>>>(bcnt, bucket_base);
    rowstart_kernel<<<(N_NODES + 255) / 256, 256, 0, stream>>>(deg, bucket_base, bcur,
                                                               row_start, cur, dis);
    passB_kernel<<<NBUCKET * PB_BLOCKS_PER, 256, 0, stream>>>(rec, bcnt, cur, esrc);

    gemm_kernel<<<(N_NODES + 63) / 64, 256, 0, stream>>>(x, W, flag, dis, h);

    aggregate_kernel<<<(N_NODES + 3) / 4, 256, 0, stream>>>(esrc, row_start, deg, dis, bfv,
                                                            flag, h, d_out);
}

// Round 6
// 395.213 us; speedup vs baseline: 3.3499x; 3.3499x over previous
//
#include <hip/hip_runtime.h>

#define N_NODES 100000
#define N_EDGES 1600000
#define D 128
#define NBUCKET 8
#define BUCKET_W 12500          // N_NODES / NBUCKET
#define CAP 216000              // per-bucket record capacity (E/8=200k, 38 sigma margin)
#define CHUNK 2048              // edges per binA block
#define PB_BLOCKS_PER 192       // passB blocks per bucket
#define SCAN_BLOCKS ((N_NODES + 255) / 256)   // 391

typedef __attribute__((ext_vector_type(8))) short short8;
typedef __attribute__((ext_vector_type(4))) float float4v;

__device__ inline unsigned short f2bf(float f) {
    unsigned u = __float_as_uint(f);
    unsigned r = (u + 0x7fffu + ((u >> 16) & 1u)) >> 16;   // RNE
    return (unsigned short)r;
}
__device__ inline float bflo(unsigned int p) { return __uint_as_float(p << 16); }
__device__ inline float bfhi(unsigned int p) { return __uint_as_float(p & 0xffff0000u); }

// dtype probe: bf16 (flag=1) vs fp32 (flag=0)
__global__ void probe_kernel(const unsigned int* __restrict__ xw, int* __restrict__ flag) {
    __shared__ int cnt;
    if (threadIdx.x == 0) cnt = 0;
    __syncthreads();
    unsigned int low = xw[threadIdx.x] & 0xFFFFu;
    unsigned int e = (low >> 7) & 0xFFu;
    atomicAdd(&cnt, (e == 0u) || (e >= 107u && e <= 147u));
    __syncthreads();
    if (threadIdx.x == 0) *flag = (cnt >= 192) ? 1 : 0;
}

__global__ void convert_b_kernel(const void* __restrict__ b, const int* __restrict__ flag,
                                 float* __restrict__ bfv) {
    int i = threadIdx.x;
    if (i < D)
        bfv[i] = *flag ? bflo(((const unsigned short*)b)[i]) : ((const float*)b)[i];
}

// Pass A: coarse-bin edges into 8 buckets (block-private contiguous appends -> full-line
// writebacks); also counts deg.
__global__ void binA_kernel(const int* __restrict__ src, const int* __restrict__ dst,
                            int* __restrict__ bcnt, int* __restrict__ deg,
                            int2* __restrict__ rec) {
    __shared__ int lcnt[NBUCKET], lbase[NBUCKET];
    int tid = threadIdx.x;
    int e0 = blockIdx.x * CHUNK;
    int eend = e0 + CHUNK < N_EDGES ? e0 + CHUNK : N_EDGES;
    if (tid < NBUCKET) lcnt[tid] = 0;
    __syncthreads();
    for (int i = e0 + tid; i < eend; i += 256)
        atomicAdd(&lcnt[dst[i] / BUCKET_W], 1);
    __syncthreads();
    if (tid < NBUCKET) { lbase[tid] = atomicAdd(&bcnt[tid], lcnt[tid]); lcnt[tid] = 0; }
    __syncthreads();
    for (int i = e0 + tid; i < eend; i += 256) {
        int d = dst[i], s = src[i];
        int g = d / BUCKET_W;
        int pos = lbase[g] + atomicAdd(&lcnt[g], 1);
        if (pos < CAP) rec[(size_t)g * CAP + pos] = make_int2(s, d);
        atomicAdd(&deg[d], 1);
    }
}

// ---- row_start = exclusive_scan(deg). Buckets are contiguous node ranges, so the
// scan automatically yields bucket-contiguous esrc regions. NO contended atomics
// (R5 lesson: 100k atomics on 8 cursors = 919 us of serialized L2 RMW).
__global__ void scan1_kernel(const int* __restrict__ deg, int* __restrict__ row_start,
                             int* __restrict__ blk_sum) {
    __shared__ int tmp[256];
    int i = blockIdx.x * 256 + threadIdx.x;
    int v = (i < N_NODES) ? deg[i] : 0;
    tmp[threadIdx.x] = v;
    __syncthreads();
    for (int off = 1; off < 256; off <<= 1) {
        int t = (threadIdx.x >= off) ? tmp[threadIdx.x - off] : 0;
        __syncthreads();
        tmp[threadIdx.x] += t;
        __syncthreads();
    }
    if (i < N_NODES) row_start[i] = tmp[threadIdx.x] - v;   // block-local exclusive
    if (threadIdx.x == 255) blk_sum[blockIdx.x] = tmp[255];
}

__global__ void scan2_kernel(int* __restrict__ blk_sum) {
    __shared__ int tmp[512];
    int tid = threadIdx.x;
    int v = (tid < SCAN_BLOCKS) ? blk_sum[tid] : 0;
    tmp[tid] = v;
    __syncthreads();
    for (int off = 1; off < 512; off <<= 1) {
        int t = (tid >= off) ? tmp[tid - off] : 0;
        __syncthreads();
        tmp[tid] += t;
        __syncthreads();
    }
    if (tid < SCAN_BLOCKS) blk_sum[tid] = tmp[tid] - v;     // exclusive block offsets
}

__global__ void scan3_kernel(const int* __restrict__ blk_sum, const int* __restrict__ deg,
                             int* __restrict__ row_start, int* __restrict__ cur,
                             float* __restrict__ dis) {
    int i = blockIdx.x * 256 + threadIdx.x;
    if (i < N_NODES) {
        int rs = row_start[i] + blk_sum[blockIdx.x];
        row_start[i] = rs;
        cur[i] = rs;
        dis[i] = rsqrtf((float)(deg[i] + 1));   // +1 self-loop
    }
}

// Pass B: fine scatter, XCD-pinned (bucket = blockIdx%8) so each bucket's ~800KB fine
// region stays in ONE XCD L2 and partial-line writes merge.
__global__ void passB_kernel(const int2* __restrict__ rec, const int* __restrict__ bcnt,
                             int* __restrict__ cur, int* __restrict__ esrc) {
    int g = blockIdx.x & 7;
    int slice = blockIdx.x >> 3;
    int total = bcnt[g]; if (total > CAP) total = CAP;
    const int2* r = rec + (size_t)g * CAP;
    for (int i = slice * 256 + threadIdx.x; i < total; i += PB_BLOCKS_PER * 256) {
        int2 e = r[i];
        int pos = atomicAdd(&cur[e.y], 1);
        esrc[pos] = e.x;
    }
}

// h' = (x @ W) * dis[row] -> bf16 bits. MFMA 16x16x32 bf16, one wave per 16-row strip.
__global__ void gemm_kernel(const void* __restrict__ xv, const void* __restrict__ Wv,
                            const int* __restrict__ flag, const float* __restrict__ dis,
                            unsigned short* __restrict__ h) {
    __shared__ unsigned short Wt[D * 136];  // W transposed [col][k], stride 136
    int tid = threadIdx.x;
    int m = *flag;
    for (int idx = tid; idx < D * D; idx += 256) {
        int k = idx >> 7, c = idx & 127;
        Wt[c * 136 + k] = m ? ((const unsigned short*)Wv)[idx]
                            : f2bf(((const float*)Wv)[idx]);
    }
    __syncthreads();

    int wave = tid >> 6, lane = tid & 63;
    int row0 = (blockIdx.x * 4 + wave) * 16;
    if (row0 >= N_NODES) return;
    int r = lane & 15, quad = lane >> 4;

    short8 a[4];  // a[t][j] = x[row0+r][t*32 + quad*8 + j]
    if (m) {
        const unsigned short* xr = (const unsigned short*)xv + (size_t)(row0 + r) * D + quad * 8;
        #pragma unroll
        for (int t = 0; t < 4; ++t) a[t] = *(const short8*)(xr + t * 32);
    } else {
        const float* xr = (const float*)xv + (size_t)(row0 + r) * D + quad * 8;
        #pragma unroll
        for (int t = 0; t < 4; ++t)
            for (int j = 0; j < 8; ++j) a[t][j] = (short)f2bf(xr[t * 32 + j]);
    }

    float sc[4];
    #pragma unroll
    for (int reg = 0; reg < 4; ++reg) sc[reg] = dis[row0 + quad * 4 + reg];

    #pragma unroll
    for (int ct = 0; ct < 8; ++ct) {
        int col0 = ct * 16;
        float4v c = {0.f, 0.f, 0.f, 0.f};
        #pragma unroll
        for (int t = 0; t < 4; ++t) {
            short8 bfr = *(const short8*)&Wt[(col0 + r) * 136 + t * 32 + quad * 8];
            c = __builtin_amdgcn_mfma_f32_16x16x32_bf16(a[t], bfr, c, 0, 0, 0);
        }
        #pragma unroll
        for (int reg = 0; reg < 4; ++reg) {
            int orow = row0 + quad * 4 + reg;  // C/D: col=lane&15, row=quad*4+reg
            h[(size_t)orow * D + col0 + r] = f2bf(c[reg] * sc[reg]);
        }
    }
}

// Quarter-wave aggregate: 16 lanes x dwordx4 per h row, 4 edges in flight;
// butterfly (xor 16,32) combine; out = relu(dis[n]*acc + b).
__global__ void aggregate_kernel(const int* __restrict__ esrc, const int* __restrict__ row_start,
                                 const int* __restrict__ deg, const float* __restrict__ dis,
                                 const float* __restrict__ bfv, const int* __restrict__ flag,
                                 const unsigned short* __restrict__ h, void* __restrict__ out) {
    int n = blockIdx.x * 4 + (threadIdx.x >> 6);
    if (n >= N_NODES) return;
    int lane = threadIdx.x & 63;
    int q = lane >> 4, c16 = lane & 15;
    int colbase = c16 * 8;

    float acc[8];
    if (q == 0) {                    // self term (dis[src] folded into h')
        uint4 p = *(const uint4*)(h + (size_t)n * D + colbase);
        acc[0] = bflo(p.x); acc[1] = bfhi(p.x);
        acc[2] = bflo(p.y); acc[3] = bfhi(p.y);
        acc[4] = bflo(p.z); acc[5] = bfhi(p.z);
        acc[6] = bflo(p.w); acc[7] = bfhi(p.w);
    } else {
        #pragma unroll
        for (int i = 0; i < 8; ++i) acc[i] = 0.f;
    }

    int rs = row_start[n], dg = deg[n];
    for (int base = 0; base < dg; base += 64) {
        int rem = dg - base;
        int cnt = rem < 64 ? rem : 64;
        int e_my = (lane < cnt) ? esrc[rs + base + lane] : 0;
        for (int j = 0; j < cnt; j += 4) {
            int sl = j + q;
            int s = __shfl(e_my, sl & 63);
            if (sl < cnt) {
                uint4 p = *(const uint4*)(h + (size_t)s * D + colbase);
                acc[0] += bflo(p.x); acc[1] += bfhi(p.x);
                acc[2] += bflo(p.y); acc[3] += bfhi(p.y);
                acc[4] += bflo(p.z); acc[5] += bfhi(p.z);
                acc[6] += bflo(p.w); acc[7] += bfhi(p.w);
            }
        }
    }

    #pragma unroll
    for (int i = 0; i < 8; ++i) {
        acc[i] += __shfl_xor(acc[i], 16);
        acc[i] += __shfl_xor(acc[i], 32);
    }

    float dn = dis[n];
    float v[8];
    #pragma unroll
    for (int i = 0; i < 8; ++i) v[i] = fmaxf(dn * acc[i] + bfv[colbase + i], 0.f);

    if (*flag) {
        if (q == 0) {
            uint4 pk;
            pk.x = ((unsigned)f2bf(v[1]) << 16) | f2bf(v[0]);
            pk.y = ((unsigned)f2bf(v[3]) << 16) | f2bf(v[2]);
            pk.z = ((unsigned)f2bf(v[5]) << 16) | f2bf(v[4]);
            pk.w = ((unsigned)f2bf(v[7]) << 16) | f2bf(v[6]);
            *(uint4*)((unsigned short*)out + (size_t)n * D + colbase) = pk;
        }
    } else {
        if (q < 2) {
            float4 f;
            int off = q * 4;
            f.x = v[off]; f.y = v[off + 1]; f.z = v[off + 2]; f.w = v[off + 3];
            *(float4*)((float*)out + (size_t)n * D + colbase + off) = f;
        }
    }
}

extern "C" void kernel_launch(void* const* d_in, const int* in_sizes, int n_in,
                              void* d_out, int out_size, void* d_ws, size_t ws_size,
                              hipStream_t stream) {
    const void* x = nullptr; const int* ei = nullptr;
    const void* W = nullptr; const void* b = nullptr;
    for (int i = 0; i < n_in; ++i) {
        if      (in_sizes[i] == N_NODES * D) x  = d_in[i];
        else if (in_sizes[i] == 2 * N_EDGES) ei = (const int*)d_in[i];
        else if (in_sizes[i] == D * D)       W  = d_in[i];
        else if (in_sizes[i] == D)           b  = d_in[i];
    }
    if (!x || !ei || !W || !b) {
        x = d_in[0]; ei = (const int*)d_in[1]; W = d_in[2]; b = d_in[3];
    }
    const int* src = ei;            // edge_index[0]
    const int* dst = ei + N_EDGES;  // edge_index[1]

    // ws: flag(16) | bcnt 8 | blk_sum 391 | deg N | cur N | row_start N | dis N f32 |
    //     bfv 128 f32 | esrc E | rec 8*CAP int2 | h N*D bf16
    char* ws = (char*)d_ws;
    int*   flag      = (int*)ws;                       // 16 B
    int*   bcnt      = (int*)(ws + 16);                // 8
    int*   blk_sum   = bcnt + NBUCKET + 8;             // SCAN_BLOCKS (aligned)
    int*   deg       = blk_sum + SCAN_BLOCKS + 9;      // N (16B-aligned: 8+8+391+9=416)
    int*   cur       = deg + N_NODES;
    int*   row_start = cur + N_NODES;
    float* dis       = (float*)(row_start + N_NODES);
    float* bfv       = dis + N_NODES;
    int*   esrc      = (int*)(bfv + D);
    int2*  rec       = (int2*)(esrc + N_EDGES);
    unsigned short* h = (unsigned short*)(rec + (size_t)NBUCKET * CAP);

    hipMemsetAsync(deg, 0, sizeof(int) * N_NODES, stream);
    hipMemsetAsync(bcnt, 0, sizeof(int) * NBUCKET, stream);

    probe_kernel<<<1, 256, 0, stream>>>((const unsigned int*)x, flag);
    convert_b_kernel<<<1, 256, 0, stream>>>(b, flag, bfv);

    binA_kernel<<<(N_EDGES + CHUNK - 1) / CHUNK, 256, 0, stream>>>(src, dst, bcnt, deg, rec);

    scan1_kernel<<<SCAN_BLOCKS, 256, 0, stream>>>(deg, row_start, blk_sum);
    scan2_kernel<<<1, 512, 0, stream>>>(blk_sum);
    scan3_kernel<<<SCAN_BLOCKS, 256, 0, stream>>>(blk_sum, deg, row_start, cur, dis);

    passB_kernel<<<NBUCKET * PB_BLOCKS_PER, 256, 0, stream>>>(rec, bcnt, cur, esrc);

    gemm_kernel<<<(N_NODES + 63) / 64, 256, 0, stream>>>(x, W, flag, dis, h);

    aggregate_kernel<<<(N_NODES + 3) / 4, 256, 0, stream>>>(esrc, row_start, deg, dis, bfv,
                                                            flag, h, d_out);
}